// Round 1
// baseline (636.407 us; speedup 1.0000x reference)
//
#include <hip/hip_runtime.h>
#include <math.h>

// Gaussian splatting forward rasterizer, MI355X.
// P=2048 gaussians, 128x128 image. Output: img (3*128*128 f32) ++ radii (P f32).

#define IMG 128
#define NPIX (IMG * IMG)
#define GSTRIDE 10   // packed per-gaussian: px py ca cb cc op r g b valid
#define SORT_N 2048  // bitonic capacity (>= P)

// ---------------------------------------------------------------- preprocess
__global__ void gsplat_preprocess(const float* __restrict__ means,
                                  const float* __restrict__ feats,
                                  const float* __restrict__ ops,
                                  const float* __restrict__ scales,
                                  const float* __restrict__ rots,
                                  const float* __restrict__ vm,   // 4x4 row-major
                                  const float* __restrict__ pm,   // 4x4 row-major
                                  float* __restrict__ gU,         // P*GSTRIDE unsorted
                                  float* __restrict__ keyf,       // P depth keys
                                  float* __restrict__ radii_out,  // P
                                  int P)
{
    int i = blockIdx.x * blockDim.x + threadIdx.x;
    if (i >= P) return;

    const float W = (float)IMG, H = (float)IMG;
    const float tanfov = 0.5773502691896258f;        // tan(FOV/2)
    const float focal_x = W / (2.0f * tanfov);
    const float focal_y = H / (2.0f * tanfov);
    const float lim = 1.3f * tanfov;

    float mx = means[3 * i + 0], my = means[3 * i + 1], mz = means[3 * i + 2];

    // t = V[:3,:3] @ m + V[:3,3]
    float tx = vm[0] * mx + vm[1] * my + vm[2]  * mz + vm[3];
    float ty = vm[4] * mx + vm[5] * my + vm[6]  * mz + vm[7];
    float tz = vm[8] * mx + vm[9] * my + vm[10] * mz + vm[11];
    float depth = tz;

    // projection
    float ph0 = pm[0]  * mx + pm[1]  * my + pm[2]  * mz + pm[3];
    float ph1 = pm[4]  * mx + pm[5]  * my + pm[6]  * mz + pm[7];
    float pw  = pm[12] * mx + pm[13] * my + pm[14] * mz + pm[15];
    float rinv = 1.0f / (pw + 1e-7f);
    float px = ((ph0 * rinv + 1.0f) * W - 1.0f) * 0.5f;
    float py = ((ph1 * rinv + 1.0f) * H - 1.0f) * 0.5f;

    // quaternion -> rotation
    float qw = rots[4 * i + 0], qx = rots[4 * i + 1], qy = rots[4 * i + 2], qz = rots[4 * i + 3];
    float qn = sqrtf(qw * qw + qx * qx + qy * qy + qz * qz);
    qw /= qn; qx /= qn; qy /= qn; qz /= qn;
    float R00 = 1.0f - 2.0f * (qy * qy + qz * qz), R01 = 2.0f * (qx * qy - qw * qz), R02 = 2.0f * (qx * qz + qw * qy);
    float R10 = 2.0f * (qx * qy + qw * qz), R11 = 1.0f - 2.0f * (qx * qx + qz * qz), R12 = 2.0f * (qy * qz - qw * qx);
    float R20 = 2.0f * (qx * qz - qw * qy), R21 = 2.0f * (qy * qz + qw * qx), R22 = 1.0f - 2.0f * (qx * qx + qy * qy);

    float sx = scales[3 * i + 0], sy = scales[3 * i + 1], sz = scales[3 * i + 2];
    // M = R * diag(s); Sigma = M M^T
    float M00 = R00 * sx, M01 = R01 * sy, M02 = R02 * sz;
    float M10 = R10 * sx, M11 = R11 * sy, M12 = R12 * sz;
    float M20 = R20 * sx, M21 = R21 * sy, M22 = R22 * sz;
    float S00 = M00 * M00 + M01 * M01 + M02 * M02;
    float S01 = M00 * M10 + M01 * M11 + M02 * M12;
    float S02 = M00 * M20 + M01 * M21 + M02 * M22;
    float S11 = M10 * M10 + M11 * M11 + M12 * M12;
    float S12 = M10 * M20 + M11 * M21 + M12 * M22;
    float S22 = M20 * M20 + M21 * M21 + M22 * M22;

    // Jacobian (EWA)
    float txc = fminf(fmaxf(tx / tz, -lim), lim) * tz;
    float tyc = fminf(fmaxf(ty / tz, -lim), lim) * tz;
    float J00 = focal_x / tz, J02 = -focal_x * txc / (tz * tz);
    float J11 = focal_y / tz, J12 = -focal_y * tyc / (tz * tz);

    // Tm = J @ V[:3,:3]   (2x3)
    float T00 = J00 * vm[0] + J02 * vm[8];
    float T01 = J00 * vm[1] + J02 * vm[9];
    float T02 = J00 * vm[2] + J02 * vm[10];
    float T10 = J11 * vm[4] + J12 * vm[8];
    float T11 = J11 * vm[5] + J12 * vm[9];
    float T12 = J11 * vm[6] + J12 * vm[10];

    // cov2d = Tm @ Sigma @ Tm^T
    float U00 = T00 * S00 + T01 * S01 + T02 * S02;
    float U01 = T00 * S01 + T01 * S11 + T02 * S12;
    float U02 = T00 * S02 + T01 * S12 + T02 * S22;
    float U10 = T10 * S00 + T11 * S01 + T12 * S02;
    float U11 = T10 * S01 + T11 * S11 + T12 * S12;
    float U12 = T10 * S02 + T11 * S12 + T12 * S22;
    float C00 = U00 * T00 + U01 * T01 + U02 * T02;
    float C01 = U00 * T10 + U01 * T11 + U02 * T12;
    float C11 = U10 * T10 + U11 * T11 + U12 * T12;

    float a = C00 + 0.3f, b = C01, c = C11 + 0.3f;
    float det = a * c - b * b;
    bool valid = (depth > 0.2f) && (det > 0.0f);
    float det_s = valid ? det : 1.0f;
    float ca = c / det_s, cb = -b / det_s, cc = a / det_s;

    float mid = 0.5f * (a + c);
    float lam = mid + sqrtf(fmaxf(mid * mid - det, 0.1f));
    float radii = valid ? ceilf(3.0f * sqrtf(lam)) : 0.0f;

    const float SH_C0 = 0.28209479177387814f;
    float colr = fmaxf(SH_C0 * feats[3 * i + 0] + 0.5f, 0.0f);
    float colg = fmaxf(SH_C0 * feats[3 * i + 1] + 0.5f, 0.0f);
    float colb = fmaxf(SH_C0 * feats[3 * i + 2] + 0.5f, 0.0f);

    float* g = gU + (size_t)i * GSTRIDE;
    g[0] = px; g[1] = py; g[2] = ca; g[3] = cb; g[4] = cc;
    g[5] = valid ? ops[i] : 0.0f;
    g[6] = colr; g[7] = colg; g[8] = colb;
    g[9] = valid ? 1.0f : 0.0f;

    keyf[i] = valid ? depth : __uint_as_float(0x7f800000u); // +inf for invalid
    radii_out[i] = radii;
}

// --------------------------------------------------- bitonic sort + gather
// Stable depth sort: key = (float_bits(depth) << 32) | index. All valid depths
// are > 0.2 so positive-float bits are monotone; index tiebreak == numpy
// stable argsort. Single block, 1024 threads, SORT_N=2048 elems in LDS.
__global__ void gsplat_sort_gather(const float* __restrict__ keyf,
                                   const float* __restrict__ gU,
                                   float* __restrict__ gS,
                                   int P)
{
    __shared__ unsigned long long sk[SORT_N];
    int tid = threadIdx.x;

    for (int i = tid; i < SORT_N; i += 1024) {
        unsigned long long key;
        if (i < P) {
            unsigned int b = __float_as_uint(keyf[i]);
            key = ((unsigned long long)b << 32) | (unsigned int)i;
        } else {
            key = 0xFFFFFFFFFFFFFFFFull;
        }
        sk[i] = key;
    }
    __syncthreads();

    for (int k = 2; k <= SORT_N; k <<= 1) {
        for (int j = k >> 1; j > 0; j >>= 1) {
            #pragma unroll
            for (int half = 0; half < 2; ++half) {
                int i = tid + half * 1024;
                int ixj = i ^ j;
                if (ixj > i) {
                    bool up = ((i & k) == 0);
                    unsigned long long va = sk[i], vb = sk[ixj];
                    bool sw = up ? (va > vb) : (va < vb);
                    if (sw) { sk[i] = vb; sk[ixj] = va; }
                }
            }
            __syncthreads();
        }
    }

    for (int i = tid; i < P; i += 1024) {
        int idx = (int)(sk[i] & 0xFFFFFFFFu);
        const float* src = gU + (size_t)idx * GSTRIDE;
        float* dst = gS + (size_t)i * GSTRIDE;
        #pragma unroll
        for (int c = 0; c < GSTRIDE; ++c) dst[c] = src[c];
    }
}

// ----------------------------------------------------------------- raster
// One thread per pixel; 16x16 tile per 256-thread block; gaussians staged
// through LDS in 256-wide chunks (broadcast reads, conflict-free).
__global__ void gsplat_raster(const float* __restrict__ gS, int P,
                              float* __restrict__ img)
{
    __shared__ float sg[256 * GSTRIDE];

    int lx = threadIdx.x & 15, ly = threadIdx.x >> 4;
    int tilex = blockIdx.x & 7, tiley = blockIdx.x >> 3;
    int x = tilex * 16 + lx, y = tiley * 16 + ly;
    float gx = (float)x, gy = (float)y;

    float T = 1.0f, cr = 0.0f, cg = 0.0f, cb = 0.0f;
    bool done = false;

    for (int base = 0; base < P; base += 256) {
        int cnt = min(256, P - base);
        __syncthreads();
        for (int i = threadIdx.x; i < cnt * GSTRIDE; i += 256)
            sg[i] = gS[(size_t)base * GSTRIDE + i];
        __syncthreads();

        if (!done) {
            for (int p = 0; p < cnt; ++p) {
                const float* G = &sg[p * GSTRIDE];
                if (G[9] == 0.0f) continue;                 // invalid (sorted to end)
                float dx = gx - G[0], dy = gy - G[1];
                float power = -0.5f * (G[2] * dx * dx + G[4] * dy * dy) - G[3] * dx * dy;
                if (power > 0.0f) continue;
                float alpha = fminf(0.99f, G[5] * __expf(power));
                if (alpha < 0.00392156862745098f) continue; // 1/255
                float w = T * alpha;
                cr += w * G[6]; cg += w * G[7]; cb += w * G[8];
                T *= (1.0f - alpha);
                if (T < 1e-4f) { done = true; break; }      // err bound ~1e-4 << 0.4 thr
            }
        }
        if (__syncthreads_and((int)done)) break;
    }

    int n = y * IMG + x;
    img[n]            = cr + T;
    img[NPIX + n]     = cg + T;
    img[2 * NPIX + n] = cb + T;
}

// ------------------------------------------------------------------ launch
extern "C" void kernel_launch(void* const* d_in, const int* in_sizes, int n_in,
                              void* d_out, int out_size, void* d_ws, size_t ws_size,
                              hipStream_t stream)
{
    const float* means  = (const float*)d_in[0];
    // d_in[1] = means_2d (unused)
    const float* feats  = (const float*)d_in[2];
    const float* ops    = (const float*)d_in[3];
    const float* scales = (const float*)d_in[4];
    const float* rots   = (const float*)d_in[5];
    const float* vm     = (const float*)d_in[6];
    const float* pm     = (const float*)d_in[7];
    // d_in[8] = campos (unused), d_in[9]/[10] = H/W (fixed 128 in this instance)

    int P = in_sizes[0] / 3;   // 2048

    float* img   = (float*)d_out;            // 3*128*128
    float* radii = (float*)d_out + 3 * NPIX; // P

    float* keyf = (float*)d_ws;              // P
    float* gU   = keyf + SORT_N;             // P*GSTRIDE unsorted
    float* gS   = gU + (size_t)SORT_N * GSTRIDE; // P*GSTRIDE sorted

    gsplat_preprocess<<<(P + 255) / 256, 256, 0, stream>>>(
        means, feats, ops, scales, rots, vm, pm, gU, keyf, radii, P);

    gsplat_sort_gather<<<1, 1024, 0, stream>>>(keyf, gU, gS, P);

    gsplat_raster<<<64, 256, 0, stream>>>(gS, P, img);
}

// Round 2
// 148.837 us; speedup vs baseline: 4.2759x; 4.2759x over previous
//
#include <hip/hip_runtime.h>
#include <math.h>

// Gaussian splatting forward rasterizer, MI355X.
// P=2048 gaussians, 128x128 image. Output: img (3*128*128 f32) ++ radii (P f32).
//
// R2: chunked-composite raster. The over-composite is associative on (rgb,T):
// (c1,T1) (+) (c2,T2) = (c1 + T1*c2, T1*T2). Split sorted gaussians into K
// chunks; 64 tiles x K chunks blocks composite partials (no LDS, gaussian
// reads are block-uniform -> s_load into SGPRs); ordered K-step combine.

#define IMG 128
#define NPIX (IMG * IMG)
#define GS 12        // padded per-gaussian stride: px py ca cb cc op r g b pad pad pad
#define SORT_N 2048  // bitonic capacity (>= P)

// ---------------------------------------------------------------- preprocess
__global__ void gsplat_preprocess(const float* __restrict__ means,
                                  const float* __restrict__ feats,
                                  const float* __restrict__ ops,
                                  const float* __restrict__ scales,
                                  const float* __restrict__ rots,
                                  const float* __restrict__ vm,   // 4x4 row-major
                                  const float* __restrict__ pm,   // 4x4 row-major
                                  float* __restrict__ gU,         // P*GS unsorted
                                  float* __restrict__ keyf,       // P depth keys
                                  float* __restrict__ radii_out,  // P
                                  int P)
{
    int i = blockIdx.x * blockDim.x + threadIdx.x;
    if (i >= P) return;

    const float W = (float)IMG, H = (float)IMG;
    const float tanfov = 0.5773502691896258f;        // tan(FOV/2)
    const float focal_x = W / (2.0f * tanfov);
    const float focal_y = H / (2.0f * tanfov);
    const float lim = 1.3f * tanfov;

    float mx = means[3 * i + 0], my = means[3 * i + 1], mz = means[3 * i + 2];

    float tx = vm[0] * mx + vm[1] * my + vm[2]  * mz + vm[3];
    float ty = vm[4] * mx + vm[5] * my + vm[6]  * mz + vm[7];
    float tz = vm[8] * mx + vm[9] * my + vm[10] * mz + vm[11];
    float depth = tz;

    float ph0 = pm[0]  * mx + pm[1]  * my + pm[2]  * mz + pm[3];
    float ph1 = pm[4]  * mx + pm[5]  * my + pm[6]  * mz + pm[7];
    float pw  = pm[12] * mx + pm[13] * my + pm[14] * mz + pm[15];
    float rinv = 1.0f / (pw + 1e-7f);
    float px = ((ph0 * rinv + 1.0f) * W - 1.0f) * 0.5f;
    float py = ((ph1 * rinv + 1.0f) * H - 1.0f) * 0.5f;

    float qw = rots[4 * i + 0], qx = rots[4 * i + 1], qy = rots[4 * i + 2], qz = rots[4 * i + 3];
    float qn = sqrtf(qw * qw + qx * qx + qy * qy + qz * qz);
    qw /= qn; qx /= qn; qy /= qn; qz /= qn;
    float R00 = 1.0f - 2.0f * (qy * qy + qz * qz), R01 = 2.0f * (qx * qy - qw * qz), R02 = 2.0f * (qx * qz + qw * qy);
    float R10 = 2.0f * (qx * qy + qw * qz), R11 = 1.0f - 2.0f * (qx * qx + qz * qz), R12 = 2.0f * (qy * qz - qw * qx);
    float R20 = 2.0f * (qx * qz - qw * qy), R21 = 2.0f * (qy * qz + qw * qx), R22 = 1.0f - 2.0f * (qx * qx + qy * qy);

    float sx = scales[3 * i + 0], sy = scales[3 * i + 1], sz = scales[3 * i + 2];
    float M00 = R00 * sx, M01 = R01 * sy, M02 = R02 * sz;
    float M10 = R10 * sx, M11 = R11 * sy, M12 = R12 * sz;
    float M20 = R20 * sx, M21 = R21 * sy, M22 = R22 * sz;
    float S00 = M00 * M00 + M01 * M01 + M02 * M02;
    float S01 = M00 * M10 + M01 * M11 + M02 * M12;
    float S02 = M00 * M20 + M01 * M21 + M02 * M22;
    float S11 = M10 * M10 + M11 * M11 + M12 * M12;
    float S12 = M10 * M20 + M11 * M21 + M12 * M22;
    float S22 = M20 * M20 + M21 * M21 + M22 * M22;

    float txc = fminf(fmaxf(tx / tz, -lim), lim) * tz;
    float tyc = fminf(fmaxf(ty / tz, -lim), lim) * tz;
    float J00 = focal_x / tz, J02 = -focal_x * txc / (tz * tz);
    float J11 = focal_y / tz, J12 = -focal_y * tyc / (tz * tz);

    float T00 = J00 * vm[0] + J02 * vm[8];
    float T01 = J00 * vm[1] + J02 * vm[9];
    float T02 = J00 * vm[2] + J02 * vm[10];
    float T10 = J11 * vm[4] + J12 * vm[8];
    float T11 = J11 * vm[5] + J12 * vm[9];
    float T12 = J11 * vm[6] + J12 * vm[10];

    float U00 = T00 * S00 + T01 * S01 + T02 * S02;
    float U01 = T00 * S01 + T01 * S11 + T02 * S12;
    float U02 = T00 * S02 + T01 * S12 + T02 * S22;
    float U10 = T10 * S00 + T11 * S01 + T12 * S02;
    float U11 = T10 * S01 + T11 * S11 + T12 * S12;
    float U12 = T10 * S02 + T11 * S12 + T12 * S22;
    float C00 = U00 * T00 + U01 * T01 + U02 * T02;
    float C01 = U00 * T10 + U01 * T11 + U02 * T12;
    float C11 = U10 * T10 + U11 * T11 + U12 * T12;

    float a = C00 + 0.3f, b = C01, c = C11 + 0.3f;
    float det = a * c - b * b;
    bool valid = (depth > 0.2f) && (det > 0.0f);
    float det_s = valid ? det : 1.0f;
    float ca = c / det_s, cb = -b / det_s, cc = a / det_s;

    float mid = 0.5f * (a + c);
    float lam = mid + sqrtf(fmaxf(mid * mid - det, 0.1f));
    float radii = valid ? ceilf(3.0f * sqrtf(lam)) : 0.0f;

    const float SH_C0 = 0.28209479177387814f;
    float colr = fmaxf(SH_C0 * feats[3 * i + 0] + 0.5f, 0.0f);
    float colg = fmaxf(SH_C0 * feats[3 * i + 1] + 0.5f, 0.0f);
    float colb = fmaxf(SH_C0 * feats[3 * i + 2] + 0.5f, 0.0f);

    // Benign values for invalid: power=0, alpha=op*exp(0)=0 -> no NaN paths.
    float opv = ops[i];
    if (!valid) { px = 0.0f; py = 0.0f; ca = 0.0f; cb = 0.0f; cc = 0.0f; opv = 0.0f; }

    float* g = gU + (size_t)i * GS;
    g[0] = px; g[1] = py; g[2] = ca; g[3] = cb; g[4] = cc;
    g[5] = opv; g[6] = colr; g[7] = colg; g[8] = colb;
    g[9] = 0.0f; g[10] = 0.0f; g[11] = 0.0f;

    keyf[i] = valid ? depth : __uint_as_float(0x7f800000u); // +inf for invalid
    radii_out[i] = radii;
}

// --------------------------------------------------- bitonic sort + gather
// Stable depth sort: key = (float_bits(depth) << 32) | index.
__global__ void gsplat_sort_gather(const float* __restrict__ keyf,
                                   const float* __restrict__ gU,
                                   float* __restrict__ gS,
                                   int P)
{
    __shared__ unsigned long long sk[SORT_N];
    int tid = threadIdx.x;

    for (int i = tid; i < SORT_N; i += 1024) {
        unsigned long long key;
        if (i < P) {
            unsigned int b = __float_as_uint(keyf[i]);
            key = ((unsigned long long)b << 32) | (unsigned int)i;
        } else {
            key = 0xFFFFFFFFFFFFFFFFull;
        }
        sk[i] = key;
    }
    __syncthreads();

    for (int k = 2; k <= SORT_N; k <<= 1) {
        for (int j = k >> 1; j > 0; j >>= 1) {
            #pragma unroll
            for (int half = 0; half < 2; ++half) {
                int i = tid + half * 1024;
                int ixj = i ^ j;
                if (ixj > i) {
                    bool up = ((i & k) == 0);
                    unsigned long long va = sk[i], vb = sk[ixj];
                    bool sw = up ? (va > vb) : (va < vb);
                    if (sw) { sk[i] = vb; sk[ixj] = va; }
                }
            }
            __syncthreads();
        }
    }

    for (int i = tid; i < P; i += 1024) {
        int idx = (int)(sk[i] & 0xFFFFFFFFu);
        const float* src = gU + (size_t)idx * GS;
        float* dst = gS + (size_t)i * GS;
        #pragma unroll
        for (int c = 0; c < GS; ++c) dst[c] = src[c];
    }
}

// ----------------------------------------------------------------- raster
// Block = (tile, chunk). One thread per pixel of a 16x16 tile; composites
// `chunk` sorted gaussians [base, base+cnt) into a partial (rgb, T).
// Gaussian reads are block-uniform -> compiler emits scalar loads (SGPR
// broadcast, scalar pipe overlaps VALU). Branchless inner loop.
__global__ void gsplat_raster_chunk(const float* __restrict__ gS, int P,
                                    int chunk, float4* __restrict__ part)
{
    int lx = threadIdx.x & 15, ly = threadIdx.x >> 4;
    int tilex = blockIdx.x & 7, tiley = blockIdx.x >> 3;
    int x = tilex * 16 + lx, y = tiley * 16 + ly;
    float gx = (float)x, gy = (float)y;

    int base = blockIdx.y * chunk;
    int cnt = min(chunk, P - base);

    float T = 1.0f, cr = 0.0f, cg = 0.0f, cb = 0.0f;

    const float* Gp = gS + (size_t)base * GS;
    for (int p = 0; p < cnt; ++p) {
        const float* G = Gp + (size_t)p * GS;
        float pxv = G[0], pyv = G[1], ca = G[2], cbn = G[3], cc = G[4];
        float op = G[5], r = G[6], g = G[7], b = G[8];
        float dx = gx - pxv, dy = gy - pyv;
        float power = -0.5f * (ca * dx * dx + cc * dy * dy) - cbn * dx * dy;
        float e = __expf(fminf(power, 0.0f));
        float alpha = fminf(0.99f, op * e);
        alpha = (power > 0.0f) ? 0.0f : alpha;
        alpha = (alpha < 0.00392156862745098f) ? 0.0f : alpha;
        float w = T * alpha;
        cr = fmaf(w, r, cr);
        cg = fmaf(w, g, cg);
        cb = fmaf(w, b, cb);
        T = T * (1.0f - alpha);
    }

    int pix = y * IMG + x;
    part[(size_t)blockIdx.y * NPIX + pix] = make_float4(cr, cg, cb, T);
}

// ----------------------------------------------------------------- combine
// Ordered front-to-back merge of K chunk partials per pixel; adds T_final.
__global__ void gsplat_combine(const float4* __restrict__ part, int K,
                               float* __restrict__ img)
{
    int pix = blockIdx.x * blockDim.x + threadIdx.x;
    if (pix >= NPIX) return;
    float T = 1.0f, r = 0.0f, g = 0.0f, b = 0.0f;
    for (int c = 0; c < K; ++c) {
        float4 v = part[(size_t)c * NPIX + pix];
        r = fmaf(T, v.x, r);
        g = fmaf(T, v.y, g);
        b = fmaf(T, v.z, b);
        T *= v.w;
    }
    img[pix]            = r + T;
    img[NPIX + pix]     = g + T;
    img[2 * NPIX + pix] = b + T;
}

// ------------------------------------------------------------------ launch
extern "C" void kernel_launch(void* const* d_in, const int* in_sizes, int n_in,
                              void* d_out, int out_size, void* d_ws, size_t ws_size,
                              hipStream_t stream)
{
    const float* means  = (const float*)d_in[0];
    const float* feats  = (const float*)d_in[2];
    const float* ops    = (const float*)d_in[3];
    const float* scales = (const float*)d_in[4];
    const float* rots   = (const float*)d_in[5];
    const float* vm     = (const float*)d_in[6];
    const float* pm     = (const float*)d_in[7];

    int P = in_sizes[0] / 3;   // 2048

    float* img   = (float*)d_out;            // 3*128*128
    float* radii = (float*)d_out + 3 * NPIX; // P

    float* keyf = (float*)d_ws;                         // SORT_N floats
    float* gU   = keyf + SORT_N;                        // SORT_N*GS floats
    float* gS   = gU + (size_t)SORT_N * GS;             // SORT_N*GS floats
    float* endf = gS + (size_t)SORT_N * GS;
    size_t static_bytes = (size_t)(endf - keyf) * sizeof(float); // 204800, 16B-aligned
    float4* part = (float4*)endf;

    // Pick K chunks to fit ws: part needs K*NPIX*16 bytes.
    int K = 32;
    while (K > 1 && static_bytes + (size_t)K * NPIX * sizeof(float4) > ws_size) K >>= 1;
    int chunk = (P + K - 1) / K;

    gsplat_preprocess<<<(P + 255) / 256, 256, 0, stream>>>(
        means, feats, ops, scales, rots, vm, pm, gU, keyf, radii, P);

    gsplat_sort_gather<<<1, 1024, 0, stream>>>(keyf, gU, gS, P);

    gsplat_raster_chunk<<<dim3(64, K), 256, 0, stream>>>(gS, P, chunk, part);

    gsplat_combine<<<NPIX / 256, 256, 0, stream>>>(part, K, img);
}

// Round 3
// 128.761 us; speedup vs baseline: 4.9426x; 1.1559x over previous
//
#include <hip/hip_runtime.h>
#include <math.h>

// Gaussian splatting forward rasterizer, MI355X.
// P=2048 gaussians, 128x128 image. Output: img (3*128*128 f32) ++ radii (P f32).
//
// R3: replaced single-block bitonic sort (66 barrier stages on 1 CU) with
// O(P^2) stable rank+scatter across 32 blocks: rank_i = #{j: k_j<k_i} +
// #{j<i: k_j==k_i}  == numpy stable argsort position. 4.2M uint compares
// is ~2.5us device-wide; all LDS key reads are wave-broadcast (free).

#define IMG 128
#define NPIX (IMG * IMG)
#define GS 12        // padded per-gaussian stride: px py ca cb cc op r g b pad pad pad
#define SORT_N 2048  // key capacity (>= P), padded with 0xFFFFFFFF

// ---------------------------------------------------------------- preprocess
__global__ void gsplat_preprocess(const float* __restrict__ means,
                                  const float* __restrict__ feats,
                                  const float* __restrict__ ops,
                                  const float* __restrict__ scales,
                                  const float* __restrict__ rots,
                                  const float* __restrict__ vm,   // 4x4 row-major
                                  const float* __restrict__ pm,   // 4x4 row-major
                                  float* __restrict__ gU,         // P*GS unsorted
                                  float* __restrict__ keyf,       // P depth keys
                                  float* __restrict__ radii_out,  // P
                                  int P)
{
    int i = blockIdx.x * blockDim.x + threadIdx.x;
    if (i >= P) return;

    const float W = (float)IMG, H = (float)IMG;
    const float tanfov = 0.5773502691896258f;        // tan(FOV/2)
    const float focal_x = W / (2.0f * tanfov);
    const float focal_y = H / (2.0f * tanfov);
    const float lim = 1.3f * tanfov;

    float mx = means[3 * i + 0], my = means[3 * i + 1], mz = means[3 * i + 2];

    float tx = vm[0] * mx + vm[1] * my + vm[2]  * mz + vm[3];
    float ty = vm[4] * mx + vm[5] * my + vm[6]  * mz + vm[7];
    float tz = vm[8] * mx + vm[9] * my + vm[10] * mz + vm[11];
    float depth = tz;

    float ph0 = pm[0]  * mx + pm[1]  * my + pm[2]  * mz + pm[3];
    float ph1 = pm[4]  * mx + pm[5]  * my + pm[6]  * mz + pm[7];
    float pw  = pm[12] * mx + pm[13] * my + pm[14] * mz + pm[15];
    float rinv = 1.0f / (pw + 1e-7f);
    float px = ((ph0 * rinv + 1.0f) * W - 1.0f) * 0.5f;
    float py = ((ph1 * rinv + 1.0f) * H - 1.0f) * 0.5f;

    float qw = rots[4 * i + 0], qx = rots[4 * i + 1], qy = rots[4 * i + 2], qz = rots[4 * i + 3];
    float qn = sqrtf(qw * qw + qx * qx + qy * qy + qz * qz);
    qw /= qn; qx /= qn; qy /= qn; qz /= qn;
    float R00 = 1.0f - 2.0f * (qy * qy + qz * qz), R01 = 2.0f * (qx * qy - qw * qz), R02 = 2.0f * (qx * qz + qw * qy);
    float R10 = 2.0f * (qx * qy + qw * qz), R11 = 1.0f - 2.0f * (qx * qx + qz * qz), R12 = 2.0f * (qy * qz - qw * qx);
    float R20 = 2.0f * (qx * qz - qw * qy), R21 = 2.0f * (qy * qz + qw * qx), R22 = 1.0f - 2.0f * (qx * qx + qy * qy);

    float sx = scales[3 * i + 0], sy = scales[3 * i + 1], sz = scales[3 * i + 2];
    float M00 = R00 * sx, M01 = R01 * sy, M02 = R02 * sz;
    float M10 = R10 * sx, M11 = R11 * sy, M12 = R12 * sz;
    float M20 = R20 * sx, M21 = R21 * sy, M22 = R22 * sz;
    float S00 = M00 * M00 + M01 * M01 + M02 * M02;
    float S01 = M00 * M10 + M01 * M11 + M02 * M12;
    float S02 = M00 * M20 + M01 * M21 + M02 * M22;
    float S11 = M10 * M10 + M11 * M11 + M12 * M12;
    float S12 = M10 * M20 + M11 * M21 + M12 * M22;
    float S22 = M20 * M20 + M21 * M21 + M22 * M22;

    float txc = fminf(fmaxf(tx / tz, -lim), lim) * tz;
    float tyc = fminf(fmaxf(ty / tz, -lim), lim) * tz;
    float J00 = focal_x / tz, J02 = -focal_x * txc / (tz * tz);
    float J11 = focal_y / tz, J12 = -focal_y * tyc / (tz * tz);

    float T00 = J00 * vm[0] + J02 * vm[8];
    float T01 = J00 * vm[1] + J02 * vm[9];
    float T02 = J00 * vm[2] + J02 * vm[10];
    float T10 = J11 * vm[4] + J12 * vm[8];
    float T11 = J11 * vm[5] + J12 * vm[9];
    float T12 = J11 * vm[6] + J12 * vm[10];

    float U00 = T00 * S00 + T01 * S01 + T02 * S02;
    float U01 = T00 * S01 + T01 * S11 + T02 * S12;
    float U02 = T00 * S02 + T01 * S12 + T02 * S22;
    float U10 = T10 * S00 + T11 * S01 + T12 * S02;
    float U11 = T10 * S01 + T11 * S11 + T12 * S12;
    float U12 = T10 * S02 + T11 * S12 + T12 * S22;
    float C00 = U00 * T00 + U01 * T01 + U02 * T02;
    float C01 = U00 * T10 + U01 * T11 + U02 * T12;
    float C11 = U10 * T10 + U11 * T11 + U12 * T12;

    float a = C00 + 0.3f, b = C01, c = C11 + 0.3f;
    float det = a * c - b * b;
    bool valid = (depth > 0.2f) && (det > 0.0f);
    float det_s = valid ? det : 1.0f;
    float ca = c / det_s, cb = -b / det_s, cc = a / det_s;

    float mid = 0.5f * (a + c);
    float lam = mid + sqrtf(fmaxf(mid * mid - det, 0.1f));
    float radii = valid ? ceilf(3.0f * sqrtf(lam)) : 0.0f;

    const float SH_C0 = 0.28209479177387814f;
    float colr = fmaxf(SH_C0 * feats[3 * i + 0] + 0.5f, 0.0f);
    float colg = fmaxf(SH_C0 * feats[3 * i + 1] + 0.5f, 0.0f);
    float colb = fmaxf(SH_C0 * feats[3 * i + 2] + 0.5f, 0.0f);

    // Benign values for invalid: power=0, alpha=op*exp(0)=0 -> no NaN paths.
    float opv = ops[i];
    if (!valid) { px = 0.0f; py = 0.0f; ca = 0.0f; cb = 0.0f; cc = 0.0f; opv = 0.0f; }

    float* g = gU + (size_t)i * GS;
    g[0] = px; g[1] = py; g[2] = ca; g[3] = cb; g[4] = cc;
    g[5] = opv; g[6] = colr; g[7] = colg; g[8] = colb;
    g[9] = 0.0f; g[10] = 0.0f; g[11] = 0.0f;

    keyf[i] = valid ? depth : __uint_as_float(0x7f800000u); // +inf for invalid
    radii_out[i] = radii;
}

// ------------------------------------------------------- rank + scatter
// Stable rank: rank_i = #{j: k_j < k_i} + #{j < i: k_j == k_i}. Keys are
// positive-float bits (monotone as uint). Block = 256 thr = 64 gaussians x
// 4 key-slices of 512; all LDS key reads are wave-broadcast (same addr for
// all 64 lanes -> conflict-free). Then scatter the 48B record to slot rank.
__global__ void gsplat_rank_scatter(const float* __restrict__ keyf,
                                    const float* __restrict__ gU,
                                    float* __restrict__ gS,
                                    int P)
{
    __shared__ unsigned int sk[SORT_N];
    __shared__ int partial[256];

    int tid = threadIdx.x;
    for (int j = tid; j < SORT_N; j += 256)
        sk[j] = (j < P) ? __float_as_uint(keyf[j]) : 0xFFFFFFFFu; // pad > +inf bits
    __syncthreads();

    int g = tid & 63;          // gaussian within block
    int s = tid >> 6;          // key slice 0..3
    int i = blockIdx.x * 64 + g;
    bool act = (i < P);
    unsigned int ki = act ? sk[i] : 0u;

    const int SLICE = SORT_N / 4;          // 512
    int j0 = s * SLICE;
    const uint4* sk4 = (const uint4*)(sk + j0);

    int r = 0;
    #pragma unroll 4
    for (int q = 0; q < SLICE / 4; ++q) {
        uint4 k = sk4[q];                  // wave-broadcast ds_read_b128
        int j = j0 + 4 * q;
        r += (k.x < ki) || (k.x == ki && (j + 0) < i);
        r += (k.y < ki) || (k.y == ki && (j + 1) < i);
        r += (k.z < ki) || (k.z == ki && (j + 2) < i);
        r += (k.w < ki) || (k.w == ki && (j + 3) < i);
    }
    partial[tid] = r;
    __syncthreads();

    if (s == 0 && act) {
        int rank = partial[g] + partial[64 + g] + partial[128 + g] + partial[192 + g];
        const float4* src = (const float4*)(gU + (size_t)i * GS);
        float4* dst = (float4*)(gS + (size_t)rank * GS);
        dst[0] = src[0]; dst[1] = src[1]; dst[2] = src[2];
    }
}

// ----------------------------------------------------------------- raster
// Block = (tile, chunk). One thread per pixel of a 16x16 tile; composites
// `chunk` sorted gaussians [base, base+cnt) into a partial (rgb, T).
// Gaussian reads are block-uniform -> scalar loads; unroll for ILP.
__global__ void gsplat_raster_chunk(const float* __restrict__ gS, int P,
                                    int chunk, float4* __restrict__ part)
{
    int lx = threadIdx.x & 15, ly = threadIdx.x >> 4;
    int tilex = blockIdx.x & 7, tiley = blockIdx.x >> 3;
    int x = tilex * 16 + lx, y = tiley * 16 + ly;
    float gx = (float)x, gy = (float)y;

    int base = blockIdx.y * chunk;
    int cnt = min(chunk, P - base);

    float T = 1.0f, cr = 0.0f, cg = 0.0f, cb = 0.0f;

    const float* Gp = gS + (size_t)base * GS;
    #pragma unroll 4
    for (int p = 0; p < cnt; ++p) {
        const float* G = Gp + (size_t)p * GS;
        float pxv = G[0], pyv = G[1], ca = G[2], cbn = G[3], cc = G[4];
        float op = G[5], r = G[6], g = G[7], b = G[8];
        float dx = gx - pxv, dy = gy - pyv;
        float power = -0.5f * (ca * dx * dx + cc * dy * dy) - cbn * dx * dy;
        float e = __expf(fminf(power, 0.0f));
        float alpha = fminf(0.99f, op * e);
        alpha = (power > 0.0f) ? 0.0f : alpha;
        alpha = (alpha < 0.00392156862745098f) ? 0.0f : alpha;
        float w = T * alpha;
        cr = fmaf(w, r, cr);
        cg = fmaf(w, g, cg);
        cb = fmaf(w, b, cb);
        T = T * (1.0f - alpha);
    }

    int pix = y * IMG + x;
    part[(size_t)blockIdx.y * NPIX + pix] = make_float4(cr, cg, cb, T);
}

// ----------------------------------------------------------------- combine
// Ordered front-to-back merge of K chunk partials per pixel; adds T_final.
__global__ void gsplat_combine(const float4* __restrict__ part, int K,
                               float* __restrict__ img)
{
    int pix = blockIdx.x * blockDim.x + threadIdx.x;
    if (pix >= NPIX) return;
    float T = 1.0f, r = 0.0f, g = 0.0f, b = 0.0f;
    for (int c = 0; c < K; ++c) {
        float4 v = part[(size_t)c * NPIX + pix];
        r = fmaf(T, v.x, r);
        g = fmaf(T, v.y, g);
        b = fmaf(T, v.z, b);
        T *= v.w;
    }
    img[pix]            = r + T;
    img[NPIX + pix]     = g + T;
    img[2 * NPIX + pix] = b + T;
}

// ------------------------------------------------------------------ launch
extern "C" void kernel_launch(void* const* d_in, const int* in_sizes, int n_in,
                              void* d_out, int out_size, void* d_ws, size_t ws_size,
                              hipStream_t stream)
{
    const float* means  = (const float*)d_in[0];
    const float* feats  = (const float*)d_in[2];
    const float* ops    = (const float*)d_in[3];
    const float* scales = (const float*)d_in[4];
    const float* rots   = (const float*)d_in[5];
    const float* vm     = (const float*)d_in[6];
    const float* pm     = (const float*)d_in[7];

    int P = in_sizes[0] / 3;   // 2048

    float* img   = (float*)d_out;            // 3*128*128
    float* radii = (float*)d_out + 3 * NPIX; // P

    float* keyf = (float*)d_ws;                         // SORT_N floats
    float* gU   = keyf + SORT_N;                        // SORT_N*GS floats
    float* gS   = gU + (size_t)SORT_N * GS;             // SORT_N*GS floats
    float* endf = gS + (size_t)SORT_N * GS;
    size_t static_bytes = (size_t)(endf - keyf) * sizeof(float); // 16B-aligned
    float4* part = (float4*)endf;

    // Pick K chunks to fit ws: part needs K*NPIX*16 bytes.
    int K = 32;
    while (K > 1 && static_bytes + (size_t)K * NPIX * sizeof(float4) > ws_size) K >>= 1;
    int chunk = (P + K - 1) / K;

    gsplat_preprocess<<<(P + 255) / 256, 256, 0, stream>>>(
        means, feats, ops, scales, rots, vm, pm, gU, keyf, radii, P);

    gsplat_rank_scatter<<<(P + 63) / 64, 256, 0, stream>>>(keyf, gU, gS, P);

    gsplat_raster_chunk<<<dim3(64, K), 256, 0, stream>>>(gS, P, chunk, part);

    gsplat_combine<<<NPIX / 256, 256, 0, stream>>>(part, K, img);
}